// Round 5
// baseline (471.110 us; speedup 1.0000x reference)
//
#include <hip/hip_runtime.h>
#include <hip/hip_bf16.h>
#include <stdint.h>

// GAT forward, N=8192, IN=256, OUT=128.  Inputs fp32 (adj int32), output fp32.
// softmax_j(a1_i + a2_j | adj) == adj_ij*exp(a2_j)/sum_j adj_ij*exp(a2_j)  (a1 cancels)
// -> out = (adj @ (w*h)) / (adj @ w). One big GEMM over adj (268 MB read = floor).

typedef __attribute__((ext_vector_type(8))) short short8;
typedef __attribute__((ext_vector_type(4))) float float4v;

static __device__ __forceinline__ float bf2f(unsigned short u) {
    union { uint32_t i; float f; } v; v.i = ((uint32_t)u) << 16; return v.f;
}
static __device__ __forceinline__ unsigned short f2bf(float f) {
    union { float f; uint32_t i; } v; v.f = f;
    uint32_t r = v.i + 0x7FFFu + ((v.i >> 16) & 1u);
    return (unsigned short)(r >> 16);
}

// ---- detect: fp32 (flag=1) vs bf16 (flag=0) by bf16-exponent outlier census ----
__global__ void k_detect(const unsigned short* __restrict__ F, int* __restrict__ flag) {
    __shared__ int cnt;
    if (threadIdx.x == 0) cnt = 0;
    __syncthreads();
    int local = 0;
    for (int i = 0; i < 16; i++) {
        unsigned short u = F[threadIdx.x * 16 + i];
        int e = (u >> 7) & 0xFF;
        if (e >= 132 || (e > 0 && e <= 110)) local++;
    }
    atomicAdd(&cnt, local);
    __syncthreads();
    if (threadIdx.x == 0) *flag = (cnt > 256) ? 1 : 0;
}

// ---- WT[n][k] = bf16(W[k][n]) : 128x256 k-major ----
__global__ void k_transpose_w(const void* __restrict__ Wraw, const int* __restrict__ flagp,
                              unsigned short* __restrict__ WT) {
    __shared__ unsigned short tile[32][33];
    int is32 = *flagp;
    int tx = threadIdx.x & 31, ty = threadIdx.x >> 5;
    int n0 = blockIdx.x * 32, k0 = blockIdx.y * 32;
    for (int i = 0; i < 4; i++) {
        int k = k0 + ty + 8 * i, n = n0 + tx;
        tile[ty + 8 * i][tx] = is32 ? f2bf(((const float*)Wraw)[k * 128 + n])
                                    : ((const unsigned short*)Wraw)[k * 128 + n];
    }
    __syncthreads();
    for (int i = 0; i < 4; i++)
        WT[(size_t)(n0 + ty + 8 * i) * 256 + k0 + tx] = tile[tx][ty + 8 * i];
}

// ---- h = F @ W + b -> bf16 h[8192][128]. BM=64, BN=128, BK=64, 4 waves ----
__global__ __launch_bounds__(256) void k_h_gemm(const void* __restrict__ Fraw,
                                                const unsigned short* __restrict__ WT,
                                                const void* __restrict__ braw,
                                                const int* __restrict__ flagp,
                                                unsigned short* __restrict__ h) {
    __shared__ __align__(16) unsigned short As[64 * 72];
    __shared__ __align__(16) unsigned short Bs[128 * 72];
    __shared__ float bs[128];
    int is32 = *flagp;
    int t = threadIdx.x, lane = t & 63, wave = t >> 6;
    int rb = blockIdx.x * 64;
    if (t < 128)
        bs[t] = is32 ? ((const float*)braw)[t] : bf2f(((const unsigned short*)braw)[t]);

    float4v acc[8];
    for (int c = 0; c < 8; c++) acc[c] = (float4v)0.0f;

    for (int kt = 0; kt < 4; kt++) {
        int k0 = kt * 64;
        for (int i = 0; i < 2; i++) {                       // A: 64x64 -> bf16
            int flat = t + 256 * i, row = flat >> 3, part = flat & 7;
            uint4 v;
            if (is32) {
                const float* fp = (const float*)Fraw + (size_t)(rb + row) * 256 + k0 + part * 8;
                float4 v0 = *reinterpret_cast<const float4*>(fp);
                float4 v1 = *reinterpret_cast<const float4*>(fp + 4);
                v.x = f2bf(v0.x) | ((uint32_t)f2bf(v0.y) << 16);
                v.y = f2bf(v0.z) | ((uint32_t)f2bf(v0.w) << 16);
                v.z = f2bf(v1.x) | ((uint32_t)f2bf(v1.y) << 16);
                v.w = f2bf(v1.z) | ((uint32_t)f2bf(v1.w) << 16);
            } else {
                v = *reinterpret_cast<const uint4*>(
                    (const unsigned short*)Fraw + (size_t)(rb + row) * 256 + k0 + part * 8);
            }
            *reinterpret_cast<uint4*>(&As[row * 72 + part * 8]) = v;
        }
        for (int i = 0; i < 4; i++) {                       // B: 128x64 bf16 k-major
            int flat = t + 256 * i, n = flat >> 3, part = flat & 7;
            *reinterpret_cast<uint4*>(&Bs[n * 72 + part * 8]) =
                *reinterpret_cast<const uint4*>(WT + (size_t)n * 256 + k0 + part * 8);
        }
        __syncthreads();
        int m = lane & 15, kq = lane >> 4;
        for (int ks = 0; ks < 2; ks++) {
            short8 af = *reinterpret_cast<const short8*>(&As[(wave * 16 + m) * 72 + ks * 32 + kq * 8]);
            for (int c = 0; c < 8; c++) {
                short8 bfr = *reinterpret_cast<const short8*>(&Bs[(c * 16 + m) * 72 + ks * 32 + kq * 8]);
                acc[c] = __builtin_amdgcn_mfma_f32_16x16x32_bf16(af, bfr, acc[c], 0, 0, 0);
            }
        }
        __syncthreads();
    }
    int m = lane & 15, kq = lane >> 4;
    for (int c = 0; c < 8; c++) {
        int col = c * 16 + m;
        float bv = bs[col];
        for (int r = 0; r < 4; r++)
            h[(size_t)(rb + wave * 16 + kq * 4 + r) * 128 + col] = f2bf(acc[c][r] + bv);
    }
}

// ---- w_j = exp(h_j . a2_w + a2_b), plain VALU dot over bf16 h ----
__global__ __launch_bounds__(256) void k_w_vec(const unsigned short* __restrict__ h,
                                               const void* __restrict__ a2wraw,
                                               const void* __restrict__ a2braw,
                                               const int* __restrict__ flagp,
                                               float* __restrict__ wout) {
    __shared__ float aw[128];
    __shared__ float ab_s;
    int is32 = *flagp;
    int t = threadIdx.x;
    if (t < 128)
        aw[t] = is32 ? ((const float*)a2wraw)[t] : bf2f(((const unsigned short*)a2wraw)[t]);
    if (t == 0)
        ab_s = is32 ? ((const float*)a2braw)[0] : bf2f(((const unsigned short*)a2braw)[0]);
    __syncthreads();
    int j = blockIdx.x * 256 + t;
    const uint4* hp = reinterpret_cast<const uint4*>(h + (size_t)j * 128);
    float acc = 0.0f;
    for (int i = 0; i < 16; i++) {
        uint4 v = hp[i];
        acc += bf2f(v.x & 0xFFFF) * aw[8*i+0] + bf2f(v.x >> 16) * aw[8*i+1]
             + bf2f(v.y & 0xFFFF) * aw[8*i+2] + bf2f(v.y >> 16) * aw[8*i+3]
             + bf2f(v.z & 0xFFFF) * aw[8*i+4] + bf2f(v.z >> 16) * aw[8*i+5]
             + bf2f(v.w & 0xFFFF) * aw[8*i+6] + bf2f(v.w >> 16) * aw[8*i+7];
    }
    acc += ab_s;
    acc = fminf(fmaxf(acc, -60.0f), 60.0f);   // ratio-invariant; clamp for safety
    wout[j] = expf(acc);
}

// ---- whT[n][j] = bf16(w_j * h[j][n]), n<128, via LDS transpose ----
__global__ __launch_bounds__(256) void k_wht(const unsigned short* __restrict__ h,
                                             const float* __restrict__ wv,
                                             unsigned short* __restrict__ whT) {
    __shared__ float hs[64][65];
    __shared__ float ws_[64];
    int bx = blockIdx.x;
    int j0 = (bx >> 1) * 64, n0 = (bx & 1) * 64;
    int t = threadIdx.x;
    if (t < 64) ws_[t] = wv[j0 + t];
    for (int i = 0; i < 16; i++) {
        int flat = t + 256 * i, jj = flat >> 6, nn = flat & 63;
        hs[jj][nn] = bf2f(h[(size_t)(j0 + jj) * 128 + n0 + nn]);
    }
    __syncthreads();
    for (int i = 0; i < 16; i++) {
        int flat = t + 256 * i, nn = flat >> 6, jj = flat & 63;
        whT[(size_t)(n0 + nn) * 8192 + j0 + jj] = f2bf(hs[jj][nn] * ws_[jj]);
    }
}

// ---- whT row 128 = bf16(w_j); rows 129..143 = 0 (pad to BN=144) ----
__global__ void k_wht_tail(const float* __restrict__ wv, unsigned short* __restrict__ whT) {
    int flat = blockIdx.x * 256 + threadIdx.x;   // 16*8192
    int r = flat >> 13, j = flat & 8191;
    unsigned short v = (r == 0) ? f2bf(wv[j]) : (unsigned short)0;
    whT[(size_t)(128 + r) * 8192 + j] = v;
}

// ---- KMAIN: C[8192][144] += adj_bf16 @ whT^T. BM=64, BN=144, BK=64, split-K=8 ----
__global__ __launch_bounds__(256) void k_agg(const int* __restrict__ adj,
                                             const unsigned short* __restrict__ whT,
                                             float* __restrict__ C) {
    __shared__ __align__(16) unsigned short As[64 * 72];
    __shared__ __align__(16) unsigned short Bs[144 * 72];
    int bx = blockIdx.x;
    int rowtile = bx & 127, ksplit = bx >> 7;
    int rb = rowtile * 64;
    int t = threadIdx.x, lane = t & 63, wave = t >> 6;
    float4v acc[9];
    for (int c = 0; c < 9; c++) acc[c] = (float4v)0.0f;

    for (int kt = 0; kt < 16; kt++) {
        int k0 = ksplit * 1024 + kt * 64;
        for (int i = 0; i < 4; i++) {                       // adj int32 -> bf16 0/1
            int flat = t + 256 * i, row = flat >> 4, cg = flat & 15;
            int4 a = *reinterpret_cast<const int4*>(adj + (size_t)(rb + row) * 8192 + k0 + cg * 4);
            uint2 p;
            p.x = (a.x ? 0x3F80u : 0u) | ((a.y ? 0x3F80u : 0u) << 16);
            p.y = (a.z ? 0x3F80u : 0u) | ((a.w ? 0x3F80u : 0u) << 16);
            *reinterpret_cast<uint2*>(&As[row * 72 + cg * 4]) = p;
        }
        for (int i = 0; i < 5; i++) {                       // whT 144x64 bf16
            int flat = t + 256 * i;
            if (flat < 1152) {
                int n = flat >> 3, part = flat & 7;
                *reinterpret_cast<uint4*>(&Bs[n * 72 + part * 8]) =
                    *reinterpret_cast<const uint4*>(whT + (size_t)n * 8192 + k0 + part * 8);
            }
        }
        __syncthreads();
        int m = lane & 15, kq = lane >> 4;
        for (int ks = 0; ks < 2; ks++) {
            short8 af = *reinterpret_cast<const short8*>(&As[(wave * 16 + m) * 72 + ks * 32 + kq * 8]);
            for (int c = 0; c < 9; c++) {
                short8 bfr = *reinterpret_cast<const short8*>(&Bs[(c * 16 + m) * 72 + ks * 32 + kq * 8]);
                acc[c] = __builtin_amdgcn_mfma_f32_16x16x32_bf16(af, bfr, acc[c], 0, 0, 0);
            }
        }
        __syncthreads();
    }
    int m = lane & 15, kq = lane >> 4;
    for (int c = 0; c < 9; c++)
        for (int r = 0; r < 4; r++)
            atomicAdd(&C[(size_t)(rb + wave * 16 + kq * 4 + r) * 144 + c * 16 + m], acc[c][r]);
}

// ---- out[j][c] = fp32: C[j][c] / C[j][128]  (FIX: output is fp32, not bf16) ----
__global__ void k_epi(const float* __restrict__ C, float* __restrict__ out) {
    int flat = blockIdx.x * 256 + threadIdx.x;   // 8192*32
    int j = flat >> 5, c4 = (flat & 31) * 4;
    float4 v = *reinterpret_cast<const float4*>(C + (size_t)j * 144 + c4);
    float rden = 1.0f / C[(size_t)j * 144 + 128];
    float4 o;
    o.x = v.x * rden; o.y = v.y * rden; o.z = v.z * rden; o.w = v.w * rden;
    *reinterpret_cast<float4*>(out + (size_t)j * 128 + c4) = o;
}

extern "C" void kernel_launch(void* const* d_in, const int* in_sizes, int n_in,
                              void* d_out, int out_size, void* d_ws, size_t ws_size,
                              hipStream_t stream) {
    const void* F   = d_in[0];                    // features [8192][256] fp32
    const int*  adj = (const int*)d_in[1];        // [8192][8192] int32 0/1
    const void* W   = d_in[2];                    // [256][128] fp32
    const void* bv  = d_in[3];                    // [128]
    const void* a2w = d_in[6];                    // [128]   (a1 cancels; d_in[4],[5] unused)
    const void* a2b = d_in[7];                    // [1]
    float* out = (float*)d_out;                   // [8192][128] fp32

    // Layout (total 7,077,888 B). h/wv/WT/flag live INSIDE the Cws region but are
    // fully consumed before the Cws memset (stream-ordered), so overlap is safe.
    char* ws = (char*)d_ws;
    unsigned short* whT  = (unsigned short*)(ws);            // [0, 2,359,296)
    float*          Cws  = (float*)(ws + 2359296);           // [2,359,296, 7,077,888)
    unsigned short* h    = (unsigned short*)(ws + 2359296);  //   2,097,152 B (dead before memset)
    float*          wv   = (float*)(ws + 4456448);           //      32,768 B (dead before memset)
    unsigned short* WT   = (unsigned short*)(ws + 4489216);  //      65,536 B (dead before memset)
    int*            flag = (int*)(ws + 4554752);             //           4 B (dead before memset)

    k_detect<<<1, 256, 0, stream>>>((const unsigned short*)F, flag);
    k_transpose_w<<<dim3(4, 8), 256, 0, stream>>>(W, flag, WT);
    k_h_gemm<<<128, 256, 0, stream>>>(F, WT, bv, flag, h);
    k_w_vec<<<32, 256, 0, stream>>>(h, a2w, a2b, flag, wv);
    k_wht<<<256, 256, 0, stream>>>(h, wv, whT);
    k_wht_tail<<<512, 256, 0, stream>>>(wv, whT);
    hipMemsetAsync(Cws, 0, (size_t)8192 * 144 * sizeof(float), stream);
    k_agg<<<1024, 256, 0, stream>>>(adj, whT, Cws);
    k_epi<<<1024, 256, 0, stream>>>(Cws, out);
}